// Round 14
// baseline (483.902 us; speedup 1.0000x reference)
//
#include <hip/hip_runtime.h>

typedef unsigned short u16;
typedef unsigned int u32;
typedef short s16x8 __attribute__((ext_vector_type(8)));
typedef unsigned short u16x4 __attribute__((ext_vector_type(4)));
typedef float f32x4 __attribute__((ext_vector_type(4)));
typedef float f32x2 __attribute__((ext_vector_type(2)));

#define ATTN_SCALE 0.17677669529663687f

__device__ __forceinline__ u16 f2bf(float f) {
  union { float f; u32 i; } c; c.f = f;
  u32 r = c.i + 0x7fffu + ((c.i >> 16) & 1u);
  return (u16)(r >> 16);
}
__device__ __forceinline__ float bf2f(u16 u) {
  union { u32 i; float f; } c; c.i = ((u32)u) << 16; return c.f;
}
__device__ __forceinline__ f32x4 mfma16(s16x8 a, s16x8 b, f32x4 c) {
  return __builtin_amdgcn_mfma_f32_16x16x32_bf16(a, b, c, 0, 0, 0);
}

typedef __attribute__((address_space(1))) u32 gas_u32;
typedef __attribute__((address_space(3))) u32 las_u32;
#define GLL16(gp, lp) __builtin_amdgcn_global_load_lds((gas_u32*)(gp), (las_u32*)(lp), 16, 0, 0)

// window-order token m -> original token index (same formula forward+reverse
// since roll(-3) partition and roll(+3) reverse both reduce to (p+3)%56).
__device__ __forceinline__ int win_to_orig(int m) {
  int b = m / 3136, rem = m - b * 3136;
  int w = rem / 49, n = rem - w * 49;
  int wh = w >> 3, ww = w & 7;
  int i = n / 7, j = n - i * 7;
  int r = wh * 7 + i + 3; if (r >= 56) r -= 56;
  int c = ww * 7 + j + 3; if (c >= 56) c -= 56;
  return b * 3136 + r * 56 + c;
}

// ---------------- fp32 -> bf16 weight conversion (all 4 weights, 1 launch) -
__global__ __launch_bounds__(256) void cvt_all_kernel(
    const float* __restrict__ qkvw, const float* __restrict__ projw,
    const float* __restrict__ fc1w, const float* __restrict__ fc2w,
    u16* __restrict__ wq, u16* __restrict__ wp,
    u16* __restrict__ w1, u16* __restrict__ w2) {
  int i = blockIdx.x * 256 + threadIdx.x;
  if (i < 442368) wq[i] = f2bf(qkvw[i]);
  else if (i < 589824) wp[i - 442368] = f2bf(projw[i - 442368]);
  else if (i < 1179648) w1[i - 589824] = f2bf(fc1w[i - 589824]);
  else if (i < 1769472) w2[i - 1179648] = f2bf(fc2w[i - 1179648]);
}

// ---------------- bias+mask table: tbl[wi][h][irow 64][lr 16][ni 4] --------
__global__ __launch_bounds__(256) void mk_tbl_kernel(
    const float* __restrict__ rpb, const float* __restrict__ maskp,
    u16* __restrict__ tbl) {
  int idx = blockIdx.x * 256 + threadIdx.x;
  int wh = idx >> 12;
  int rem = idx & 4095;
  int irow = rem >> 6;
  int lr = (rem >> 2) & 15, ni = rem & 3;
  int j = ni * 16 + lr;
  int wi = wh / 12, h = wh - wi * 12;
  float val = -1e30f;
  if (irow < 49 && j < 49) {
    int yi = irow / 7, xi = irow - yi * 7;
    int yj = j / 7, xj = j - yj * 7;
    int rpi = (yi - yj + 6) * 13 + (xi - xj + 6);
    val = rpb[rpi * 12 + h] + maskp[((size_t)wi * 49 + irow) * 49 + j];
  }
  tbl[idx] = f2bf(val);
}

// ---------------- LayerNorm (fp32 or bf16 in, bf16 out), PAIR-vectorized ---
template <bool PERM, bool BFIN>
__global__ __launch_bounds__(256) void ln_kernel(
    const void* __restrict__ xin, const float* __restrict__ g,
    const float* __restrict__ bb, u16* __restrict__ xo) {
  int t = blockIdx.x * 4 + (threadIdx.x >> 6);
  int l = threadIdx.x & 63;
  int src = PERM ? win_to_orig(t) : t;
  float v0[3], v1[3];
  if (BFIN) {
    const u32* row = (const u32*)((const u16*)xin + (size_t)src * 384);
#pragma unroll
    for (int k = 0; k < 3; k++) {
      u32 pr = row[l + 64 * k];
      v0[k] = bf2f((u16)pr);
      v1[k] = bf2f((u16)(pr >> 16));
    }
  } else {
    const float* row = (const float*)xin + (size_t)src * 384;
#pragma unroll
    for (int k = 0; k < 3; k++) {
      f32x2 pr = *(const f32x2*)(row + 2 * (l + 64 * k));
      v0[k] = pr[0]; v1[k] = pr[1];
    }
  }
  float s = 0.f;
#pragma unroll
  for (int k = 0; k < 3; k++) s += v0[k] + v1[k];
#pragma unroll
  for (int d = 1; d < 64; d <<= 1) s += __shfl_xor(s, d);
  float mean = s * (1.f / 384.f);
  float q = 0.f;
#pragma unroll
  for (int k = 0; k < 3; k++) {
    float d0 = v0[k] - mean, d1 = v1[k] - mean;
    q += d0 * d0 + d1 * d1;
  }
#pragma unroll
  for (int d = 1; d < 64; d <<= 1) q += __shfl_xor(q, d);
  float rstd = rsqrtf(q * (1.f / 384.f) + 1e-5f);
  u32* orow = (u32*)(xo + (size_t)t * 384);
#pragma unroll
  for (int k = 0; k < 3; k++) {
    int p = l + 64 * k;
    f32x2 gg = *(const f32x2*)(g + 2 * p);
    f32x2 bv = *(const f32x2*)(bb + 2 * p);
    u32 o0 = f2bf((v0[k] - mean) * rstd * gg[0] + bv[0]);
    u32 o1 = f2bf((v1[k] - mean) * rstd * gg[1] + bv[1]);
    orow[p] = o0 | (o1 << 16);
  }
}

// ---------------- GEMM epilogue (shared) -----------------------------------
template <int EPI>
__device__ __forceinline__ void gemm_epi(
    float v, size_t m, int col, int N, int dst,
    u16* __restrict__ outb, float* __restrict__ outf,
    const float* __restrict__ auxf, const u16* __restrict__ auxb) {
  if (EPI == 0) {
    outb[m * (size_t)N + col] = f2bf(v);
  } else if (EPI == 1) {
    outb[(size_t)dst * 384 + col] = f2bf(v + auxf[(size_t)dst * 384 + col]);
  } else if (EPI == 2) {
    // gelu(v) ~= v * sigmoid(2*0.79788456*(v + 0.044715 v^3))
    float u = v * (0.7978845608028654f + 0.0356774081f * v * v);
    float gl = v / (1.f + __expf(-2.f * u));
    outb[m * (size_t)N + col] = f2bf(gl);
  } else {
    outf[m * (size_t)N + col] = v + bf2f(auxb[m * (size_t)N + col]);
  }
}

// ---------------- 256x128 BK=64 phase-interleaved GEMM (T3+T4 faithful) ----
// 8 waves as 4x2 (64x64/wave). Triple-buffered K-tiles: compute tile t,
// stage tile t+2 into the buffer tile t-1 vacated; per tile 2 phases, each
// {issue 3 gload_lds || ds_reads || lgkm(0) || 16 MFMA || barrier};
// vmcnt(6) ONCE per K-tile (1 full tile stays in flight), vmcnt(0) only on
// the last. 8-chunk XOR swizzle (chunk^row&7) via pre-swizzled global src.
template <int EPI>
__global__ __launch_bounds__(512) void gemm8p_kernel(
    const u16* __restrict__ A, const u16* __restrict__ W,
    const float* __restrict__ bias, u16* __restrict__ outb,
    float* __restrict__ outf, const float* __restrict__ auxf,
    const u16* __restrict__ auxb, int K, int N, int NT, int NB) {
  __shared__ __align__(16) short As[3 * 16384];   // 3 x (256x64)
  __shared__ __align__(16) short Bs[3 * 8192];    // 3 x (128x64)
  const int tid = threadIdx.x, wv = tid >> 6, l = tid & 63;
  const int lr = l & 15, lg = l >> 4;
  int bm, bn;
  {
    const int STS = NT << 3;
    const int body = (NB >> 3) * STS;
    int d = blockIdx.x;
    if (d < body) {
      int st = d / STS, rem = d - st * STS;
      bn = rem >> 3;
      bm = st * 8 + (rem & 7);
    } else {
      int t = d - body;
      int tq = t / NT;
      bm = (NB & ~7) + tq;
      bn = t - tq * NT;
    }
  }
  const size_t m0 = (size_t)bm * 256, n0 = (size_t)bn * 128;
  // staging: round r covers rows r*64 + wv*8 + (l>>3); lane chunk (l&7),
  // source chunk pre-swizzled by row&7 = (l>>3). LDS stays linear.
  const int srow = wv * 8 + (l >> 3);
  const int schk = ((l & 7) ^ (l >> 3)) << 3;
  const u16* gaA = A + (m0 + srow) * K + schk;
  const u16* gaB = W + (n0 + srow) * K + schk;
  const int stoff = wv * 512;                      // wave's 1KB slice per round
  const int wr = wv >> 1, wc = wv & 1;             // 4x2 wave grid, 64x64/wave
  const int rsw = (lr & 7) << 3;                   // read-side chunk swizzle

  const int nt = K >> 6;
  // prologue: stage tiles 0 and 1 (6 loads each per wave)
#pragma unroll
  for (int tt = 0; tt < 2; ++tt) {
#pragma unroll
    for (int r = 0; r < 4; r++)
      GLL16(gaA + (size_t)r * 64 * K + tt * 64, As + tt * 16384 + r * 4096 + stoff);
#pragma unroll
    for (int r = 0; r < 2; r++)
      GLL16(gaB + (size_t)r * 64 * K + tt * 64, Bs + tt * 8192 + r * 4096 + stoff);
  }

  f32x4 acc[4][4] = {};
  s16x8 af[2][2], bfr[4][2];
  for (int t = 0; t < nt; ++t) {
    const int bt = t % 3;
    const int st = t + 2, sb = st % 3;
    const short* as = As + bt * 16384;
    const short* bs = Bs + bt * 8192;
    // ---------- phase 0: tile ready wait (counted), stage half, B+A01, MFMA
    if (t + 1 < nt) { asm volatile("s_waitcnt vmcnt(6)" ::: "memory"); }
    else            { asm volatile("s_waitcnt vmcnt(0)" ::: "memory"); }
    __builtin_amdgcn_sched_barrier(0);
    __builtin_amdgcn_s_barrier();          // tile t resident; buf sb free
    if (st < nt) {
      GLL16(gaA + st * 64, As + sb * 16384 + stoff);
      GLL16(gaA + (size_t)64 * K + st * 64, As + sb * 16384 + 4096 + stoff);
      GLL16(gaB + st * 64, Bs + sb * 8192 + stoff);
    }
#pragma unroll
    for (int ni = 0; ni < 4; ni++)
#pragma unroll
      for (int kk = 0; kk < 2; kk++)
        bfr[ni][kk] = *(const s16x8*)&bs[(wc * 64 + ni * 16 + lr) * 64 +
                                         (((kk * 4 + lg) << 3) ^ rsw)];
#pragma unroll
    for (int mi = 0; mi < 2; mi++)
#pragma unroll
      for (int kk = 0; kk < 2; kk++)
        af[mi][kk] = *(const s16x8*)&as[(wr * 64 + mi * 16 + lr) * 64 +
                                        (((kk * 4 + lg) << 3) ^ rsw)];
    asm volatile("s_waitcnt lgkmcnt(0)" ::: "memory");
    __builtin_amdgcn_sched_barrier(0);
    __builtin_amdgcn_s_setprio(1);
#pragma unroll
    for (int mi = 0; mi < 2; mi++)
#pragma unroll
      for (int ni = 0; ni < 4; ni++)
#pragma unroll
        for (int kk = 0; kk < 2; kk++)
          acc[mi][ni] = mfma16(af[mi][kk], bfr[ni][kk], acc[mi][ni]);
    __builtin_amdgcn_s_setprio(0);
    __builtin_amdgcn_s_barrier();
    // ---------- phase 1: stage other half, A23, MFMA
    if (st < nt) {
      GLL16(gaA + (size_t)128 * K + st * 64, As + sb * 16384 + 8192 + stoff);
      GLL16(gaA + (size_t)192 * K + st * 64, As + sb * 16384 + 12288 + stoff);
      GLL16(gaB + (size_t)64 * K + st * 64, Bs + sb * 8192 + 4096 + stoff);
    }
#pragma unroll
    for (int mi = 0; mi < 2; mi++)
#pragma unroll
      for (int kk = 0; kk < 2; kk++)
        af[mi][kk] = *(const s16x8*)&as[(wr * 64 + (mi + 2) * 16 + lr) * 64 +
                                        (((kk * 4 + lg) << 3) ^ rsw)];
    asm volatile("s_waitcnt lgkmcnt(0)" ::: "memory");
    __builtin_amdgcn_sched_barrier(0);
    __builtin_amdgcn_s_setprio(1);
#pragma unroll
    for (int mi = 0; mi < 2; mi++)
#pragma unroll
      for (int ni = 0; ni < 4; ni++)
#pragma unroll
        for (int kk = 0; kk < 2; kk++)
          acc[mi + 2][ni] = mfma16(af[mi][kk], bfr[ni][kk], acc[mi + 2][ni]);
    __builtin_amdgcn_s_setprio(0);
    __builtin_amdgcn_s_barrier();
  }

  const int colb = (int)n0 + wc * 64;
#pragma unroll
  for (int mi = 0; mi < 4; mi++) {
#pragma unroll
    for (int r = 0; r < 4; r++) {
      const size_t m = m0 + wr * 64 + mi * 16 + lg * 4 + r;
      int dst = 0;
      if (EPI == 1) dst = win_to_orig((int)m);
#pragma unroll
      for (int ni = 0; ni < 4; ni++) {
        const int col = colb + ni * 16 + lr;
        gemm_epi<EPI>(acc[mi][ni][r] + bias[col], m, col, N, dst,
                      outb, outf, auxf, auxb);
      }
    }
  }
}

// ---------------- 128x128 BK=32 GEMM (r6/r10-proven 2-buffer) --------------
template <int EPI>
__global__ __launch_bounds__(256) void gemm128_kernel(
    const u16* __restrict__ A, const u16* __restrict__ W,
    const float* __restrict__ bias, u16* __restrict__ outb,
    float* __restrict__ outf, const float* __restrict__ auxf,
    const u16* __restrict__ auxb, int K, int N, int NT, int NB) {
  __shared__ __align__(16) short As[8192];
  __shared__ __align__(16) short Bs[8192];
  const int tid = threadIdx.x, wv = tid >> 6, l = tid & 63;
  const int lr = l & 15, lg = l >> 4;
  int bm, bn;
  {
    const int STS = NT << 3;
    const int body = (NB >> 3) * STS;
    int d = blockIdx.x;
    if (d < body) {
      int st = d / STS, rem = d - st * STS;
      bn = rem >> 3;
      bm = st * 8 + (rem & 7);
    } else {
      int t = d - body;
      int tq = t / NT;
      bm = (NB & ~7) + tq;
      bn = t - tq * NT;
    }
  }
  const size_t m0 = (size_t)bm * 128, n0 = (size_t)bn * 128;
  const int prow = wv * 16 + (l >> 2);
  const int ccl = (((l & 3) ^ ((l >> 3) & 3)) << 3);
  const u16* ga0 = A + (m0 + prow) * K + ccl;
  const u16* ga1 = A + (m0 + 64 + prow) * K + ccl;
  const u16* gb0 = W + (n0 + prow) * K + ccl;
  const u16* gb1 = W + (n0 + 64 + prow) * K + ccl;
  const int stoff = wv * 512;
  const int wr = wv >> 1, wc = wv & 1;
  const int sw = (lr >> 1) & 3;
  const int aoff = (wr * 64 + lr) * 32 + ((lg ^ sw) << 3);
  const int boff = (wc * 64 + lr) * 32 + ((lg ^ sw) << 3);

#define STAGE(bufo, koff)                            \
  do {                                               \
    GLL16(ga0 + (koff), As + (bufo) + stoff);        \
    GLL16(ga1 + (koff), As + (bufo) + 2048 + stoff); \
    GLL16(gb0 + (koff), Bs + (bufo) + stoff);        \
    GLL16(gb1 + (koff), Bs + (bufo) + 2048 + stoff); \
  } while (0)
#define FRAG_READS(cur)                                              \
  do {                                                               \
    const short* as = As + (cur);                                    \
    const short* bs = Bs + (cur);                                    \
    _Pragma("unroll") for (int mi = 0; mi < 4; mi++)                 \
        af[mi] = *(const s16x8*)&as[aoff + mi * 512];                \
    _Pragma("unroll") for (int ni = 0; ni < 4; ni++)                 \
        bfr[ni] = *(const s16x8*)&bs[boff + ni * 512];               \
  } while (0)
#define MFMA_TILE()                                        \
  do {                                                     \
    _Pragma("unroll") for (int mi = 0; mi < 4; mi++)       \
        _Pragma("unroll") for (int ni = 0; ni < 4; ni++)   \
            acc[mi][ni] = mfma16(af[mi], bfr[ni], acc[mi][ni]); \
  } while (0)

  f32x4 acc[4][4] = {};
  s16x8 af[4], bfr[4];
  STAGE(0, 0);
  STAGE(4096, 32);
  int cur = 0;
  int k0 = 0;
  for (; k0 < K - 32; k0 += 32) {
    asm volatile("s_waitcnt vmcnt(4)" ::: "memory");
    __builtin_amdgcn_sched_barrier(0);
    __builtin_amdgcn_s_barrier();
    FRAG_READS(cur);
    asm volatile("s_waitcnt lgkmcnt(0)" ::: "memory");
    __builtin_amdgcn_sched_barrier(0);
    __builtin_amdgcn_s_barrier();
    if (k0 + 64 < K) STAGE(cur, k0 + 64);
    MFMA_TILE();
    cur ^= 4096;
  }
  asm volatile("s_waitcnt vmcnt(0)" ::: "memory");
  __builtin_amdgcn_sched_barrier(0);
  __builtin_amdgcn_s_barrier();
  FRAG_READS(cur);
  asm volatile("s_waitcnt lgkmcnt(0)" ::: "memory");
  __builtin_amdgcn_sched_barrier(0);
  MFMA_TILE();
#undef STAGE
#undef FRAG_READS
#undef MFMA_TILE

  const int colb = (int)n0 + wc * 64;
#pragma unroll
  for (int mi = 0; mi < 4; mi++) {
#pragma unroll
    for (int r = 0; r < 4; r++) {
      const size_t m = m0 + wr * 64 + mi * 16 + lg * 4 + r;
      int dst = 0;
      if (EPI == 1) dst = win_to_orig((int)m);
#pragma unroll
      for (int ni = 0; ni < 4; ni++) {
        const int col = colb + ni * 16 + lr;
        gemm_epi<EPI>(acc[mi][ni][r] + bias[col], m, col, N, dst,
                      outb, outf, auxf, auxb);
      }
    }
  }
}

// ---------------- windowed attention: 1 wave per (window, head) ------------
__global__ __launch_bounds__(256) void attn_kernel(
    const u16* __restrict__ qkv, const u16* __restrict__ tbl,
    u16* __restrict__ out) {
  __shared__ __align__(16) short Pl[4][16 * 76];
  const int tid = threadIdx.x, wv = tid >> 6, l = tid & 63;
  const int lr = l & 15, lg = l >> 4;

  const int task = blockIdx.x * 4 + wv;
  const int win = task / 12, h = task - win * 12;
  const int wi = win & 63;
  const short* base = (const short*)qkv + (size_t)win * 49 * 1152 + h * 32;
  const u16* tb = tbl + (size_t)(wi * 12 + h) * 4096 + lr * 4;

  s16x8 qf[4], kf[4];
  const s16x8 zz = {0, 0, 0, 0, 0, 0, 0, 0};
#pragma unroll
  for (int mi = 0; mi < 4; mi++) {
    int n = mi * 16 + lr;
    if (n < 49) {
      qf[mi] = *(const s16x8*)(base + (size_t)n * 1152 + lg * 8);
      kf[mi] = *(const s16x8*)(base + (size_t)n * 1152 + 384 + lg * 8);
    } else { qf[mi] = zz; kf[mi] = zz; }
  }
  s16x8 vb[2][2];
#pragma unroll
  for (int kk = 0; kk < 2; kk++)
#pragma unroll
    for (int nd = 0; nd < 2; nd++)
#pragma unroll
      for (int e = 0; e < 8; e++)
        vb[kk][nd][e] = base[(size_t)(kk * 32 + lg * 8 + e) * 1152 + 768 + nd * 16 + lr];
  u16x4 t4[4][4];
#pragma unroll
  for (int r = 0; r < 4; r++)
    t4[0][r] = *(const u16x4*)&tb[(lg * 4 + r) * 64];

  f32x4 acc[4][4] = {};
  __builtin_amdgcn_s_setprio(1);
#pragma unroll
  for (int mi = 0; mi < 4; mi++)
#pragma unroll
    for (int ni = 0; ni < 4; ni++)
      acc[mi][ni] = mfma16(qf[mi], kf[ni], acc[mi][ni]);
  __builtin_amdgcn_s_setprio(0);

  short* pl = Pl[wv];
#pragma unroll
  for (int mi = 0; mi < 4; mi++) {
    if (mi < 3) {
#pragma unroll
      for (int r = 0; r < 4; r++)
        t4[mi + 1][r] = *(const u16x4*)&tb[((mi + 1) * 16 + lg * 4 + r) * 64];
    }
    float rs[4];
#pragma unroll
    for (int r = 0; r < 4; r++) {
      float sv[4];
#pragma unroll
      for (int ni = 0; ni < 4; ni++)
        sv[ni] = acc[mi][ni][r] * ATTN_SCALE + bf2f(t4[mi][r][ni]);
      float mx = fmaxf(fmaxf(sv[0], sv[1]), fmaxf(sv[2], sv[3]));
#pragma unroll
      for (int d = 1; d < 16; d <<= 1) mx = fmaxf(mx, __shfl_xor(mx, d));
      float sm = 0.f;
#pragma unroll
      for (int ni = 0; ni < 4; ni++) { sv[ni] = __expf(sv[ni] - mx); sm += sv[ni]; }
#pragma unroll
      for (int d = 1; d < 16; d <<= 1) sm += __shfl_xor(sm, d);
      rs[r] = 1.f / sm;
#pragma unroll
      for (int ni = 0; ni < 4; ni++)
        pl[(lg * 4 + r) * 76 + ni * 16 + lr] = (short)f2bf(sv[ni]);
    }
    f32x4 o[2] = {{}, {}};
    __builtin_amdgcn_s_setprio(1);
#pragma unroll
    for (int kk = 0; kk < 2; kk++) {
      s16x8 pa = *(const s16x8*)&pl[lr * 76 + kk * 32 + lg * 8];
#pragma unroll
      for (int nd = 0; nd < 2; nd++)
        o[nd] = mfma16(pa, vb[kk][nd], o[nd]);
    }
    __builtin_amdgcn_s_setprio(0);
#pragma unroll
    for (int r = 0; r < 4; r++) {
      const int irow = mi * 16 + lg * 4 + r;
      if (irow < 49) {
#pragma unroll
        for (int nd = 0; nd < 2; nd++)
          out[((size_t)win * 49 + irow) * 384 + h * 32 + nd * 16 + lr] =
              f2bf(o[nd][r] * rs[r]);
      }
    }
  }
}

extern "C" void kernel_launch(void* const* d_in, const int* in_sizes, int n_in,
                              void* d_out, int out_size, void* d_ws, size_t ws_size,
                              hipStream_t stream) {
  (void)in_sizes; (void)n_in; (void)out_size; (void)ws_size;
  const float* x     = (const float*)d_in[0];
  const float* maskp = (const float*)d_in[1];
  const float* n1g   = (const float*)d_in[2];
  const float* n1b   = (const float*)d_in[3];
  const float* qkvw  = (const float*)d_in[4];
  const float* qkvb  = (const float*)d_in[5];
  const float* rpb   = (const float*)d_in[6];
  const float* projw = (const float*)d_in[7];
  const float* projb = (const float*)d_in[8];
  const float* n2g   = (const float*)d_in[9];
  const float* n2b   = (const float*)d_in[10];
  const float* fc1w  = (const float*)d_in[11];
  const float* fc1b  = (const float*)d_in[12];
  const float* fc2w  = (const float*)d_in[13];
  const float* fc2b  = (const float*)d_in[14];
  float* outp = (float*)d_out;

  // workspace layout, lifetime-shared (r10-proven):
  char* ws = (char*)d_ws;
  u16*  regA  = (u16*)ws;
  u16*  regB  = (u16*)(ws + 154140672ull);
  u16*  tbl   = (u16*)(ws + 192675840ull);
  u16*  xresb = (u16*)(ws + 192675840ull);
  u16*  wq = (u16*)(ws + 231211008ull);
  u16*  wp = wq + 442368;
  u16*  w1 = wp + 147456;
  u16*  w2 = w1 + 589824;

  // 0. weights fp32 -> bf16 + bias/mask table
  cvt_all_kernel<<<6912, 256, 0, stream>>>(qkvw, projw, fc1w, fc2w, wq, wp, w1, w2);
  mk_tbl_kernel<<<12288, 256, 0, stream>>>(rpb, maskp, tbl);
  // 1. LN1 + cyclic shift + window partition (fp32 -> bf16, window order)
  ln_kernel<true, false><<<12544, 256, 0, stream>>>(x, n1g, n1b, regB);
  // 2. QKV projection: (50176x384) @ (384x1152), phase-interleaved template
  gemm8p_kernel<0><<<196 * 9, 512, 0, stream>>>(regB, wq, qkvb, regA, nullptr,
                                                nullptr, nullptr, 384, 1152, 9, 196);
  // 3. windowed attention
  attn_kernel<<<3072, 256, 0, stream>>>(regA, tbl, regB);
  // 4. output projection + fp32-x shortcut, un-permute -> bf16 residual (C)
  gemm128_kernel<1><<<392 * 3, 256, 0, stream>>>(regB, wp, projb, xresb, nullptr,
                                                 x, nullptr, 384, 384, 3, 392);
  // 5. LN2 (bf16 xres -> bf16 xln2 in B)
  ln_kernel<false, true><<<12544, 256, 0, stream>>>(xresb, n2g, n2b, regB);
  // 6. FC1 + GELU, full M: (50176x384)@(384x1536), phase-interleaved template
  gemm8p_kernel<2><<<196 * 12, 512, 0, stream>>>(regB, w1, fc1b, regA, nullptr,
                                                 nullptr, nullptr, 384, 1536, 12, 196);
  // 7. FC2 + residual, full M -> final fp32 output
  gemm128_kernel<3><<<392 * 3, 256, 0, stream>>>(regA, w2, fc2b, nullptr, outp,
                                                 nullptr, xresb, 1536, 384, 3, 392);
}

// Round 15
// 406.642 us; speedup vs baseline: 1.1900x; 1.1900x over previous
//
#include <hip/hip_runtime.h>

typedef unsigned short u16;
typedef unsigned int u32;
typedef short s16x8 __attribute__((ext_vector_type(8)));
typedef unsigned short u16x4 __attribute__((ext_vector_type(4)));
typedef float f32x4 __attribute__((ext_vector_type(4)));

#define ATTN_SCALE 0.17677669529663687f

__device__ __forceinline__ u16 f2bf(float f) {
  union { float f; u32 i; } c; c.f = f;
  u32 r = c.i + 0x7fffu + ((c.i >> 16) & 1u);
  return (u16)(r >> 16);
}
__device__ __forceinline__ float bf2f(u16 u) {
  union { u32 i; float f; } c; c.i = ((u32)u) << 16; return c.f;
}
__device__ __forceinline__ f32x4 mfma16(s16x8 a, s16x8 b, f32x4 c) {
  return __builtin_amdgcn_mfma_f32_16x16x32_bf16(a, b, c, 0, 0, 0);
}

typedef __attribute__((address_space(1))) u32 gas_u32;
typedef __attribute__((address_space(3))) u32 las_u32;
#define GLL16(gp, lp) __builtin_amdgcn_global_load_lds((gas_u32*)(gp), (las_u32*)(lp), 16, 0, 0)

// window-order token m -> original token index (same formula forward+reverse
// since roll(-3) partition and roll(+3) reverse both reduce to (p+3)%56).
__device__ __forceinline__ int win_to_orig(int m) {
  int b = m / 3136, rem = m - b * 3136;
  int w = rem / 49, n = rem - w * 49;
  int wh = w >> 3, ww = w & 7;
  int i = n / 7, j = n - i * 7;
  int r = wh * 7 + i + 3; if (r >= 56) r -= 56;
  int c = ww * 7 + j + 3; if (c >= 56) c -= 56;
  return b * 3136 + r * 56 + c;
}

// ---------------- fp32 -> bf16 weight conversion (all 4 weights, 1 launch) -
__global__ __launch_bounds__(256) void cvt_all_kernel(
    const float* __restrict__ qkvw, const float* __restrict__ projw,
    const float* __restrict__ fc1w, const float* __restrict__ fc2w,
    u16* __restrict__ wq, u16* __restrict__ wp,
    u16* __restrict__ w1, u16* __restrict__ w2) {
  int i = blockIdx.x * 256 + threadIdx.x;
  if (i < 442368) wq[i] = f2bf(qkvw[i]);
  else if (i < 589824) wp[i - 442368] = f2bf(projw[i - 442368]);
  else if (i < 1179648) w1[i - 589824] = f2bf(fc1w[i - 589824]);
  else if (i < 1769472) w2[i - 1179648] = f2bf(fc2w[i - 1179648]);
}

// ---------------- bias+mask table: tbl[wi][h][irow 64][lr 16][ni 4] --------
__global__ __launch_bounds__(256) void mk_tbl_kernel(
    const float* __restrict__ rpb, const float* __restrict__ maskp,
    u16* __restrict__ tbl) {
  int idx = blockIdx.x * 256 + threadIdx.x;   // (wi*12+h)*4096 + irow*64 + lr*4 + ni
  int wh = idx >> 12;
  int rem = idx & 4095;
  int irow = rem >> 6;
  int lr = (rem >> 2) & 15, ni = rem & 3;
  int j = ni * 16 + lr;
  int wi = wh / 12, h = wh - wi * 12;
  float val = -1e30f;
  if (irow < 49 && j < 49) {
    int yi = irow / 7, xi = irow - yi * 7;
    int yj = j / 7, xj = j - yj * 7;
    int rpi = (yi - yj + 6) * 13 + (xi - xj + 6);
    val = rpb[rpi * 12 + h] + maskp[((size_t)wi * 49 + irow) * 49 + j];
  }
  tbl[idx] = f2bf(val);
}

// ---------------- LayerNorm (fp32 or bf16 in, bf16 out) --------------------
template <bool PERM, bool BFIN>
__global__ __launch_bounds__(256) void ln_kernel(
    const void* __restrict__ xin, const float* __restrict__ g,
    const float* __restrict__ bb, u16* __restrict__ xo) {
  int t = blockIdx.x * 4 + (threadIdx.x >> 6);
  int l = threadIdx.x & 63;
  int src = PERM ? win_to_orig(t) : t;
  float v[6];
  if (BFIN) {
    const u16* row = (const u16*)xin + (size_t)src * 384;
#pragma unroll
    for (int k = 0; k < 6; k++) v[k] = bf2f(row[l + 64 * k]);
  } else {
    const float* row = (const float*)xin + (size_t)src * 384;
#pragma unroll
    for (int k = 0; k < 6; k++) v[k] = row[l + 64 * k];
  }
  float s = 0.f;
#pragma unroll
  for (int k = 0; k < 6; k++) s += v[k];
#pragma unroll
  for (int d = 1; d < 64; d <<= 1) s += __shfl_xor(s, d);
  float mean = s * (1.f / 384.f);
  float q = 0.f;
#pragma unroll
  for (int k = 0; k < 6; k++) { float dv = v[k] - mean; q += dv * dv; }
#pragma unroll
  for (int d = 1; d < 64; d <<= 1) q += __shfl_xor(q, d);
  float rstd = rsqrtf(q * (1.f / 384.f) + 1e-5f);
  u16* orow = xo + (size_t)t * 384;
#pragma unroll
  for (int k = 0; k < 6; k++) {
    int c = l + 64 * k;
    orow[c] = f2bf((v[k] - mean) * rstd * g[c] + bb[c]);
  }
}

// ---------------- GEMM epilogue (shared) -----------------------------------
template <int EPI>
__device__ __forceinline__ void gemm_epi(
    float v, size_t m, int col, int N, int dst,
    u16* __restrict__ outb, float* __restrict__ outf,
    const float* __restrict__ auxf, const u16* __restrict__ auxb) {
  if (EPI == 0) {
    outb[m * (size_t)N + col] = f2bf(v);
  } else if (EPI == 1) {
    outb[(size_t)dst * 384 + col] = f2bf(v + auxf[(size_t)dst * 384 + col]);
  } else if (EPI == 2) {
    // gelu(v) ~= v * sigmoid(2*0.79788456*(v + 0.044715 v^3))
    float u = v * (0.7978845608028654f + 0.0356774081f * v * v);
    float gl = v / (1.f + __expf(-2.f * u));
    outb[m * (size_t)N + col] = f2bf(gl);
  } else {
    outf[m * (size_t)N + col] = v + bf2f(auxb[m * (size_t)N + col]);
  }
}

// ---------------- 128x128 BK=32 GEMM (r6-proven template) ------------------
// 2-tile-deep counted-vmcnt pipeline; supertile-XCD swizzle; for the
// small-N GEMMs (proj, fc2) where block count matters most.
template <int EPI>
__global__ __launch_bounds__(256) void gemm128_kernel(
    const u16* __restrict__ A, const u16* __restrict__ W,
    const float* __restrict__ bias, u16* __restrict__ outb,
    float* __restrict__ outf, const float* __restrict__ auxf,
    const u16* __restrict__ auxb, int K, int N, int NT, int NB) {
  __shared__ __align__(16) short As[8192];   // 2 x (128x32)
  __shared__ __align__(16) short Bs[8192];
  const int tid = threadIdx.x, wv = tid >> 6, l = tid & 63;
  const int lr = l & 15, lg = l >> 4;
  int bm, bn;
  {
    const int STS = NT << 3;
    const int body = (NB >> 3) * STS;
    int d = blockIdx.x;
    if (d < body) {
      int st = d / STS, rem = d - st * STS;
      bn = rem >> 3;
      bm = st * 8 + (rem & 7);
    } else {
      int t = d - body;
      int tq = t / NT;
      bm = (NB & ~7) + tq;
      bn = t - tq * NT;
    }
  }
  const size_t m0 = (size_t)bm * 128, n0 = (size_t)bn * 128;
  const int prow = wv * 16 + (l >> 2);
  const int ccl = (((l & 3) ^ ((l >> 3) & 3)) << 3);
  const u16* ga0 = A + (m0 + prow) * K + ccl;
  const u16* ga1 = A + (m0 + 64 + prow) * K + ccl;
  const u16* gb0 = W + (n0 + prow) * K + ccl;
  const u16* gb1 = W + (n0 + 64 + prow) * K + ccl;
  const int stoff = wv * 512;
  const int wr = wv >> 1, wc = wv & 1;
  const int sw = (lr >> 1) & 3;
  const int aoff = (wr * 64 + lr) * 32 + ((lg ^ sw) << 3);
  const int boff = (wc * 64 + lr) * 32 + ((lg ^ sw) << 3);

#define STAGE(bufo, koff)                            \
  do {                                               \
    GLL16(ga0 + (koff), As + (bufo) + stoff);        \
    GLL16(ga1 + (koff), As + (bufo) + 2048 + stoff); \
    GLL16(gb0 + (koff), Bs + (bufo) + stoff);        \
    GLL16(gb1 + (koff), Bs + (bufo) + 2048 + stoff); \
  } while (0)
#define FRAG_READS(cur)                                              \
  do {                                                               \
    const short* as = As + (cur);                                    \
    const short* bs = Bs + (cur);                                    \
    _Pragma("unroll") for (int mi = 0; mi < 4; mi++)                 \
        af[mi] = *(const s16x8*)&as[aoff + mi * 512];                \
    _Pragma("unroll") for (int ni = 0; ni < 4; ni++)                 \
        bfr[ni] = *(const s16x8*)&bs[boff + ni * 512];               \
  } while (0)
#define MFMA_TILE()                                        \
  do {                                                     \
    _Pragma("unroll") for (int mi = 0; mi < 4; mi++)       \
        _Pragma("unroll") for (int ni = 0; ni < 4; ni++)   \
            acc[mi][ni] = mfma16(af[mi], bfr[ni], acc[mi][ni]); \
  } while (0)

  f32x4 acc[4][4] = {};
  s16x8 af[4], bfr[4];
  STAGE(0, 0);
  STAGE(4096, 32);                      // 8 loads in flight
  int cur = 0;
  int k0 = 0;
  for (; k0 < K - 32; k0 += 32) {
    asm volatile("s_waitcnt vmcnt(4)" ::: "memory");
    __builtin_amdgcn_sched_barrier(0);
    __builtin_amdgcn_s_barrier();
    FRAG_READS(cur);
    asm volatile("s_waitcnt lgkmcnt(0)" ::: "memory");
    __builtin_amdgcn_sched_barrier(0);
    __builtin_amdgcn_s_barrier();
    if (k0 + 64 < K) STAGE(cur, k0 + 64);
    MFMA_TILE();
    cur ^= 4096;
  }
  asm volatile("s_waitcnt vmcnt(0)" ::: "memory");
  __builtin_amdgcn_sched_barrier(0);
  __builtin_amdgcn_s_barrier();
  FRAG_READS(cur);
  asm volatile("s_waitcnt lgkmcnt(0)" ::: "memory");
  __builtin_amdgcn_sched_barrier(0);
  MFMA_TILE();
#undef STAGE
#undef FRAG_READS
#undef MFMA_TILE

  const int colb = (int)n0 + wc * 64;
#pragma unroll
  for (int mi = 0; mi < 4; mi++) {
#pragma unroll
    for (int r = 0; r < 4; r++) {
      const size_t m = m0 + wr * 64 + mi * 16 + lg * 4 + r;
      int dst = 0;
      if (EPI == 1) dst = win_to_orig((int)m);
#pragma unroll
      for (int ni = 0; ni < 4; ni++) {
        const int col = colb + ni * 16 + lr;
        gemm_epi<EPI>(acc[mi][ni][r] + bias[col], m, col, N, dst,
                      outb, outf, auxf, auxb);
      }
    }
  }
}

// ---------------- 256x128 BK=32 GEMM, 8 waves (r7-proven template) ---------
// Wave grid 2x4: wave (wr,wc) owns rows wr*128+[0,128), cols wc*32+[0,32).
// For the large-block-count GEMMs (qkv, fc1).
template <int EPI>
__global__ __launch_bounds__(512) void gemm256_kernel(
    const u16* __restrict__ A, const u16* __restrict__ W,
    const float* __restrict__ bias, u16* __restrict__ outb,
    float* __restrict__ outf, const float* __restrict__ auxf,
    const u16* __restrict__ auxb, int K, int N, int NT, int NB) {
  __shared__ __align__(16) short As[16384];   // 2 x (256x32)
  __shared__ __align__(16) short Bs[8192];    // 2 x (128x32)
  const int tid = threadIdx.x, wv = tid >> 6, l = tid & 63;
  const int lr = l & 15, lg = l >> 4;
  int bm, bn;
  {
    const int STS = NT << 3;
    const int body = (NB >> 3) * STS;
    int d = blockIdx.x;
    if (d < body) {
      int st = d / STS, rem = d - st * STS;
      bn = rem >> 3;
      bm = st * 8 + (rem & 7);
    } else {
      int t = d - body;
      int tq = t / NT;
      bm = (NB & ~7) + tq;
      bn = t - tq * NT;
    }
  }
  const size_t m0 = (size_t)bm * 256, n0 = (size_t)bn * 128;
  const int prow = wv * 16 + (l >> 2);
  const int ccl = (((l & 3) ^ ((l >> 3) & 3)) << 3);
  const u16* ga0 = A + (m0 + prow) * K + ccl;
  const u16* ga1 = A + (m0 + 128 + prow) * K + ccl;
  const u16* gb0 = W + (n0 + prow) * K + ccl;
  const int stoff = wv * 512;
  const int wr = wv >> 2, wc = wv & 3;
  const int sw = (lr >> 1) & 3;
  const int aoff = (wr * 128 + lr) * 32 + ((lg ^ sw) << 3);
  const int boff = (wc * 32 + lr) * 32 + ((lg ^ sw) << 3);

#define STAGE(c, koff)                                     \
  do {                                                     \
    GLL16(ga0 + (koff), As + (c) * 8192 + stoff);          \
    GLL16(ga1 + (koff), As + (c) * 8192 + 4096 + stoff);   \
    GLL16(gb0 + (koff), Bs + (c) * 4096 + stoff);          \
  } while (0)
#define FRAG_READS(c)                                                \
  do {                                                               \
    const short* as = As + (c) * 8192;                               \
    const short* bs = Bs + (c) * 4096;                               \
    _Pragma("unroll") for (int mi = 0; mi < 8; mi++)                 \
        af[mi] = *(const s16x8*)&as[aoff + mi * 512];                \
    _Pragma("unroll") for (int ni = 0; ni < 2; ni++)                 \
        bfr[ni] = *(const s16x8*)&bs[boff + ni * 512];               \
  } while (0)
#define MFMA_TILE()                                        \
  do {                                                     \
    __builtin_amdgcn_s_setprio(1);                         \
    _Pragma("unroll") for (int mi = 0; mi < 8; mi++)       \
        _Pragma("unroll") for (int ni = 0; ni < 2; ni++)   \
            acc[mi][ni] = mfma16(af[mi], bfr[ni], acc[mi][ni]); \
    __builtin_amdgcn_s_setprio(0);                         \
  } while (0)

  f32x4 acc[8][2] = {};
  s16x8 af[8], bfr[2];
  STAGE(0, 0);
  STAGE(1, 32);                         // 6 loads in flight
  int cur = 0;
  int k0 = 0;
  for (; k0 < K - 32; k0 += 32) {
    asm volatile("s_waitcnt vmcnt(3)" ::: "memory");
    __builtin_amdgcn_sched_barrier(0);
    __builtin_amdgcn_s_barrier();
    FRAG_READS(cur);
    asm volatile("s_waitcnt lgkmcnt(0)" ::: "memory");
    __builtin_amdgcn_sched_barrier(0);
    __builtin_amdgcn_s_barrier();
    if (k0 + 64 < K) STAGE(cur, k0 + 64);
    MFMA_TILE();
    cur ^= 1;
  }
  asm volatile("s_waitcnt vmcnt(0)" ::: "memory");
  __builtin_amdgcn_sched_barrier(0);
  __builtin_amdgcn_s_barrier();
  FRAG_READS(cur);
  asm volatile("s_waitcnt lgkmcnt(0)" ::: "memory");
  __builtin_amdgcn_sched_barrier(0);
  MFMA_TILE();
#undef STAGE
#undef FRAG_READS
#undef MFMA_TILE

  const int colb = (int)n0 + wc * 32;
#pragma unroll
  for (int mi = 0; mi < 8; mi++) {
#pragma unroll
    for (int r = 0; r < 4; r++) {
      const size_t m = m0 + wr * 128 + mi * 16 + lg * 4 + r;
      int dst = 0;
      if (EPI == 1) dst = win_to_orig((int)m);
#pragma unroll
      for (int ni = 0; ni < 2; ni++) {
        const int col = colb + ni * 16 + lr;
        gemm_epi<EPI>(acc[mi][ni][r] + bias[col], m, col, N, dst,
                      outb, outf, auxf, auxb);
      }
    }
  }
}

// ---------------- windowed attention: 1 wave per (window, head) ------------
__global__ __launch_bounds__(256) void attn_kernel(
    const u16* __restrict__ qkv, const u16* __restrict__ tbl,
    u16* __restrict__ out) {
  __shared__ __align__(16) short Pl[4][16 * 76];
  const int tid = threadIdx.x, wv = tid >> 6, l = tid & 63;
  const int lr = l & 15, lg = l >> 4;

  const int task = blockIdx.x * 4 + wv;          // < 12288 exactly
  const int win = task / 12, h = task - win * 12;
  const int wi = win & 63;
  const short* base = (const short*)qkv + (size_t)win * 49 * 1152 + h * 32;
  const u16* tb = tbl + (size_t)(wi * 12 + h) * 4096 + lr * 4;

  s16x8 qf[4], kf[4];
  const s16x8 zz = {0, 0, 0, 0, 0, 0, 0, 0};
#pragma unroll
  for (int mi = 0; mi < 4; mi++) {
    int n = mi * 16 + lr;
    if (n < 49) {
      qf[mi] = *(const s16x8*)(base + (size_t)n * 1152 + lg * 8);
      kf[mi] = *(const s16x8*)(base + (size_t)n * 1152 + 384 + lg * 8);
    } else { qf[mi] = zz; kf[mi] = zz; }
  }
  s16x8 vb[2][2];
#pragma unroll
  for (int kk = 0; kk < 2; kk++)
#pragma unroll
    for (int nd = 0; nd < 2; nd++)
#pragma unroll
      for (int e = 0; e < 8; e++)
        vb[kk][nd][e] = base[(size_t)(kk * 32 + lg * 8 + e) * 1152 + 768 + nd * 16 + lr];
  u16x4 t4[4][4];
#pragma unroll
  for (int r = 0; r < 4; r++)
    t4[0][r] = *(const u16x4*)&tb[(lg * 4 + r) * 64];

  f32x4 acc[4][4] = {};
  __builtin_amdgcn_s_setprio(1);
#pragma unroll
  for (int mi = 0; mi < 4; mi++)
#pragma unroll
    for (int ni = 0; ni < 4; ni++)
      acc[mi][ni] = mfma16(qf[mi], kf[ni], acc[mi][ni]);
  __builtin_amdgcn_s_setprio(0);

  short* pl = Pl[wv];
#pragma unroll
  for (int mi = 0; mi < 4; mi++) {
    if (mi < 3) {
#pragma unroll
      for (int r = 0; r < 4; r++)
        t4[mi + 1][r] = *(const u16x4*)&tb[((mi + 1) * 16 + lg * 4 + r) * 64];
    }
    float rs[4];
#pragma unroll
    for (int r = 0; r < 4; r++) {
      float sv[4];
#pragma unroll
      for (int ni = 0; ni < 4; ni++)
        sv[ni] = acc[mi][ni][r] * ATTN_SCALE + bf2f(t4[mi][r][ni]);
      float mx = fmaxf(fmaxf(sv[0], sv[1]), fmaxf(sv[2], sv[3]));
#pragma unroll
      for (int d = 1; d < 16; d <<= 1) mx = fmaxf(mx, __shfl_xor(mx, d));
      float sm = 0.f;
#pragma unroll
      for (int ni = 0; ni < 4; ni++) { sv[ni] = __expf(sv[ni] - mx); sm += sv[ni]; }
#pragma unroll
      for (int d = 1; d < 16; d <<= 1) sm += __shfl_xor(sm, d);
      rs[r] = 1.f / sm;
#pragma unroll
      for (int ni = 0; ni < 4; ni++)
        pl[(lg * 4 + r) * 76 + ni * 16 + lr] = (short)f2bf(sv[ni]);
    }
    f32x4 o[2] = {{}, {}};
    __builtin_amdgcn_s_setprio(1);
#pragma unroll
    for (int kk = 0; kk < 2; kk++) {
      s16x8 pa = *(const s16x8*)&pl[lr * 76 + kk * 32 + lg * 8];
#pragma unroll
      for (int nd = 0; nd < 2; nd++)
        o[nd] = mfma16(pa, vb[kk][nd], o[nd]);
    }
    __builtin_amdgcn_s_setprio(0);
#pragma unroll
    for (int r = 0; r < 4; r++) {
      const int irow = mi * 16 + lg * 4 + r;
      if (irow < 49) {
#pragma unroll
        for (int nd = 0; nd < 2; nd++)
          out[((size_t)win * 49 + irow) * 384 + h * 32 + nd * 16 + lr] =
              f2bf(o[nd][r] * rs[r]);
      }
    }
  }
}

extern "C" void kernel_launch(void* const* d_in, const int* in_sizes, int n_in,
                              void* d_out, int out_size, void* d_ws, size_t ws_size,
                              hipStream_t stream) {
  (void)in_sizes; (void)n_in; (void)out_size; (void)ws_size;
  const float* x     = (const float*)d_in[0];
  const float* maskp = (const float*)d_in[1];
  const float* n1g   = (const float*)d_in[2];
  const float* n1b   = (const float*)d_in[3];
  const float* qkvw  = (const float*)d_in[4];
  const float* qkvb  = (const float*)d_in[5];
  const float* rpb   = (const float*)d_in[6];
  const float* projw = (const float*)d_in[7];
  const float* projb = (const float*)d_in[8];
  const float* n2g   = (const float*)d_in[9];
  const float* n2b   = (const float*)d_in[10];
  const float* fc1w  = (const float*)d_in[11];
  const float* fc1b  = (const float*)d_in[12];
  const float* fc2w  = (const float*)d_in[13];
  const float* fc2b  = (const float*)d_in[14];
  float* outp = (float*)d_out;

  // workspace layout, lifetime-shared (r10-proven):
  // A [0, 154140672): qkv (115.6 MB) then h2 (exactly 154.14 MB)
  // B [154140672, +38535168): xw -> attn_out -> xln2
  // C [192675840, +38535168): tbl (6.3 MB, dead after attn) -> xres
  // D [231211008, +3538944): bf16 weights
  char* ws = (char*)d_ws;
  u16*  regA  = (u16*)ws;
  u16*  regB  = (u16*)(ws + 154140672ull);
  u16*  tbl   = (u16*)(ws + 192675840ull);
  u16*  xresb = (u16*)(ws + 192675840ull);
  u16*  wq = (u16*)(ws + 231211008ull);
  u16*  wp = wq + 442368;
  u16*  w1 = wp + 147456;
  u16*  w2 = w1 + 589824;

  // 0. weights fp32 -> bf16 + bias/mask table
  cvt_all_kernel<<<6912, 256, 0, stream>>>(qkvw, projw, fc1w, fc2w, wq, wp, w1, w2);
  mk_tbl_kernel<<<12288, 256, 0, stream>>>(rpb, maskp, tbl);
  // 1. LN1 + cyclic shift + window partition (fp32 -> bf16, window order)
  ln_kernel<true, false><<<12544, 256, 0, stream>>>(x, n1g, n1b, regB);
  // 2. QKV projection: (50176x384) @ (384x1152), 256-row tiles
  gemm256_kernel<0><<<196 * 9, 512, 0, stream>>>(regB, wq, qkvb, regA, nullptr,
                                                 nullptr, nullptr, 384, 1152, 9, 196);
  // 3. windowed attention (qkv in A, tbl in C, attn_out -> B)
  attn_kernel<<<3072, 256, 0, stream>>>(regA, tbl, regB);
  // 4. output projection + fp32-x shortcut, un-permute -> bf16 residual (C)
  gemm128_kernel<1><<<392 * 3, 256, 0, stream>>>(regB, wp, projb, xresb, nullptr,
                                                 x, nullptr, 384, 384, 3, 392);
  // 5. LN2 (bf16 xres -> bf16 xln2 in B)
  ln_kernel<false, true><<<12544, 256, 0, stream>>>(xresb, n2g, n2b, regB);
  // 6. FC1 + GELU, full M: (50176x384)@(384x1536) -> h2 in A (qkv dead)
  gemm256_kernel<2><<<196 * 12, 512, 0, stream>>>(regB, w1, fc1b, regA, nullptr,
                                                  nullptr, nullptr, 384, 1536, 12, 196);
  // 7. FC2 + residual, full M -> final fp32 output
  gemm128_kernel<3><<<392 * 3, 256, 0, stream>>>(regA, w2, fc2b, nullptr, outp,
                                                 nullptr, xresb, 1536, 384, 3, 392);
}

// Round 16
// 404.546 us; speedup vs baseline: 1.1962x; 1.0052x over previous
//
#include <hip/hip_runtime.h>

typedef unsigned short u16;
typedef unsigned int u32;
typedef short s16x8 __attribute__((ext_vector_type(8)));
typedef unsigned short u16x4 __attribute__((ext_vector_type(4)));
typedef float f32x4 __attribute__((ext_vector_type(4)));

#define ATTN_SCALE 0.17677669529663687f

__device__ __forceinline__ u16 f2bf(float f) {
  union { float f; u32 i; } c; c.f = f;
  u32 r = c.i + 0x7fffu + ((c.i >> 16) & 1u);
  return (u16)(r >> 16);
}
__device__ __forceinline__ float bf2f(u16 u) {
  union { u32 i; float f; } c; c.i = ((u32)u) << 16; return c.f;
}
__device__ __forceinline__ f32x4 mfma16(s16x8 a, s16x8 b, f32x4 c) {
  return __builtin_amdgcn_mfma_f32_16x16x32_bf16(a, b, c, 0, 0, 0);
}

typedef __attribute__((address_space(1))) u32 gas_u32;
typedef __attribute__((address_space(3))) u32 las_u32;
#define GLL16(gp, lp) __builtin_amdgcn_global_load_lds((gas_u32*)(gp), (las_u32*)(lp), 16, 0, 0)

// window-order token m -> original token index (same formula forward+reverse
// since roll(-3) partition and roll(+3) reverse both reduce to (p+3)%56).
__device__ __forceinline__ int win_to_orig(int m) {
  int b = m / 3136, rem = m - b * 3136;
  int w = rem / 49, n = rem - w * 49;
  int wh = w >> 3, ww = w & 7;
  int i = n / 7, j = n - i * 7;
  int r = wh * 7 + i + 3; if (r >= 56) r -= 56;
  int c = ww * 7 + j + 3; if (c >= 56) c -= 56;
  return b * 3136 + r * 56 + c;
}

// ---------------- prologue: weight cvt + bias/mask table in ONE launch -----
// blocks [0,6912): fp32->bf16 of all 4 weights; blocks [6912,19200):
// tbl[wi][h][irow 64][lr 16][ni 4] = rpb[rpi]+mask (-1e30 on pads).
__global__ __launch_bounds__(256) void prolog_kernel(
    const float* __restrict__ qkvw, const float* __restrict__ projw,
    const float* __restrict__ fc1w, const float* __restrict__ fc2w,
    u16* __restrict__ wq, u16* __restrict__ wp,
    u16* __restrict__ w1, u16* __restrict__ w2,
    const float* __restrict__ rpb, const float* __restrict__ maskp,
    u16* __restrict__ tbl) {
  if (blockIdx.x < 6912) {
    int i = blockIdx.x * 256 + threadIdx.x;
    if (i < 442368) wq[i] = f2bf(qkvw[i]);
    else if (i < 589824) wp[i - 442368] = f2bf(projw[i - 442368]);
    else if (i < 1179648) w1[i - 589824] = f2bf(fc1w[i - 589824]);
    else if (i < 1769472) w2[i - 1179648] = f2bf(fc2w[i - 1179648]);
  } else {
    int idx = (blockIdx.x - 6912) * 256 + threadIdx.x;
    int wh = idx >> 12;
    int rem = idx & 4095;
    int irow = rem >> 6;
    int lr = (rem >> 2) & 15, ni = rem & 3;
    int j = ni * 16 + lr;
    int wi = wh / 12, h = wh - wi * 12;
    float val = -1e30f;
    if (irow < 49 && j < 49) {
      int yi = irow / 7, xi = irow - yi * 7;
      int yj = j / 7, xj = j - yj * 7;
      int rpi = (yi - yj + 6) * 13 + (xi - xj + 6);
      val = rpb[rpi * 12 + h] + maskp[((size_t)wi * 49 + irow) * 49 + j];
    }
    tbl[idx] = f2bf(val);
  }
}

// ---------------- LayerNorm (fp32 or bf16 in, bf16 out) --------------------
template <bool PERM, bool BFIN>
__global__ __launch_bounds__(256) void ln_kernel(
    const void* __restrict__ xin, const float* __restrict__ g,
    const float* __restrict__ bb, u16* __restrict__ xo) {
  int t = blockIdx.x * 4 + (threadIdx.x >> 6);
  int l = threadIdx.x & 63;
  int src = PERM ? win_to_orig(t) : t;
  float v[6];
  if (BFIN) {
    const u16* row = (const u16*)xin + (size_t)src * 384;
#pragma unroll
    for (int k = 0; k < 6; k++) v[k] = bf2f(row[l + 64 * k]);
  } else {
    const float* row = (const float*)xin + (size_t)src * 384;
#pragma unroll
    for (int k = 0; k < 6; k++) v[k] = row[l + 64 * k];
  }
  float s = 0.f;
#pragma unroll
  for (int k = 0; k < 6; k++) s += v[k];
#pragma unroll
  for (int d = 1; d < 64; d <<= 1) s += __shfl_xor(s, d);
  float mean = s * (1.f / 384.f);
  float q = 0.f;
#pragma unroll
  for (int k = 0; k < 6; k++) { float dv = v[k] - mean; q += dv * dv; }
#pragma unroll
  for (int d = 1; d < 64; d <<= 1) q += __shfl_xor(q, d);
  float rstd = rsqrtf(q * (1.f / 384.f) + 1e-5f);
  u16* orow = xo + (size_t)t * 384;
#pragma unroll
  for (int k = 0; k < 6; k++) {
    int c = l + 64 * k;
    orow[c] = f2bf((v[k] - mean) * rstd * g[c] + bb[c]);
  }
}

// ---------------- GEMM epilogue (shared) -----------------------------------
template <int EPI>
__device__ __forceinline__ void gemm_epi(
    float v, size_t m, int col, int N, int dst,
    u16* __restrict__ outb, float* __restrict__ outf,
    const float* __restrict__ auxf, const u16* __restrict__ auxb) {
  if (EPI == 0) {
    outb[m * (size_t)N + col] = f2bf(v);
  } else if (EPI == 1) {
    outb[(size_t)dst * 384 + col] = f2bf(v + auxf[(size_t)dst * 384 + col]);
  } else if (EPI == 2) {
    // gelu(v) ~= v * sigmoid(2*0.79788456*(v + 0.044715 v^3))
    float u = v * (0.7978845608028654f + 0.0356774081f * v * v);
    float gl = v / (1.f + __expf(-2.f * u));
    outb[m * (size_t)N + col] = f2bf(gl);
  } else {
    outf[m * (size_t)N + col] = v + bf2f(auxb[m * (size_t)N + col]);
  }
}

// ---------------- 128x128 BK=32 GEMM (r6-proven template) ------------------
// 2-tile-deep counted-vmcnt pipeline; supertile-XCD swizzle; for the
// small-N GEMMs (proj, fc2) where block count matters most.
template <int EPI>
__global__ __launch_bounds__(256) void gemm128_kernel(
    const u16* __restrict__ A, const u16* __restrict__ W,
    const float* __restrict__ bias, u16* __restrict__ outb,
    float* __restrict__ outf, const float* __restrict__ auxf,
    const u16* __restrict__ auxb, int K, int N, int NT, int NB) {
  __shared__ __align__(16) short As[8192];   // 2 x (128x32)
  __shared__ __align__(16) short Bs[8192];
  const int tid = threadIdx.x, wv = tid >> 6, l = tid & 63;
  const int lr = l & 15, lg = l >> 4;
  int bm, bn;
  {
    const int STS = NT << 3;
    const int body = (NB >> 3) * STS;
    int d = blockIdx.x;
    if (d < body) {
      int st = d / STS, rem = d - st * STS;
      bn = rem >> 3;
      bm = st * 8 + (rem & 7);
    } else {
      int t = d - body;
      int tq = t / NT;
      bm = (NB & ~7) + tq;
      bn = t - tq * NT;
    }
  }
  const size_t m0 = (size_t)bm * 128, n0 = (size_t)bn * 128;
  const int prow = wv * 16 + (l >> 2);
  const int ccl = (((l & 3) ^ ((l >> 3) & 3)) << 3);
  const u16* ga0 = A + (m0 + prow) * K + ccl;
  const u16* ga1 = A + (m0 + 64 + prow) * K + ccl;
  const u16* gb0 = W + (n0 + prow) * K + ccl;
  const u16* gb1 = W + (n0 + 64 + prow) * K + ccl;
  const int stoff = wv * 512;
  const int wr = wv >> 1, wc = wv & 1;
  const int sw = (lr >> 1) & 3;
  const int aoff = (wr * 64 + lr) * 32 + ((lg ^ sw) << 3);
  const int boff = (wc * 64 + lr) * 32 + ((lg ^ sw) << 3);

#define STAGE(bufo, koff)                            \
  do {                                               \
    GLL16(ga0 + (koff), As + (bufo) + stoff);        \
    GLL16(ga1 + (koff), As + (bufo) + 2048 + stoff); \
    GLL16(gb0 + (koff), Bs + (bufo) + stoff);        \
    GLL16(gb1 + (koff), Bs + (bufo) + 2048 + stoff); \
  } while (0)
#define FRAG_READS(cur)                                              \
  do {                                                               \
    const short* as = As + (cur);                                    \
    const short* bs = Bs + (cur);                                    \
    _Pragma("unroll") for (int mi = 0; mi < 4; mi++)                 \
        af[mi] = *(const s16x8*)&as[aoff + mi * 512];                \
    _Pragma("unroll") for (int ni = 0; ni < 4; ni++)                 \
        bfr[ni] = *(const s16x8*)&bs[boff + ni * 512];               \
  } while (0)
#define MFMA_TILE()                                        \
  do {                                                     \
    _Pragma("unroll") for (int mi = 0; mi < 4; mi++)       \
        _Pragma("unroll") for (int ni = 0; ni < 4; ni++)   \
            acc[mi][ni] = mfma16(af[mi], bfr[ni], acc[mi][ni]); \
  } while (0)

  f32x4 acc[4][4] = {};
  s16x8 af[4], bfr[4];
  STAGE(0, 0);
  STAGE(4096, 32);                      // 8 loads in flight
  int cur = 0;
  int k0 = 0;
  for (; k0 < K - 32; k0 += 32) {
    asm volatile("s_waitcnt vmcnt(4)" ::: "memory");
    __builtin_amdgcn_sched_barrier(0);
    __builtin_amdgcn_s_barrier();
    FRAG_READS(cur);
    asm volatile("s_waitcnt lgkmcnt(0)" ::: "memory");
    __builtin_amdgcn_sched_barrier(0);
    __builtin_amdgcn_s_barrier();
    if (k0 + 64 < K) STAGE(cur, k0 + 64);
    MFMA_TILE();
    cur ^= 4096;
  }
  asm volatile("s_waitcnt vmcnt(0)" ::: "memory");
  __builtin_amdgcn_sched_barrier(0);
  __builtin_amdgcn_s_barrier();
  FRAG_READS(cur);
  asm volatile("s_waitcnt lgkmcnt(0)" ::: "memory");
  __builtin_amdgcn_sched_barrier(0);
  MFMA_TILE();
#undef STAGE
#undef FRAG_READS
#undef MFMA_TILE

  const int colb = (int)n0 + wc * 64;
#pragma unroll
  for (int mi = 0; mi < 4; mi++) {
#pragma unroll
    for (int r = 0; r < 4; r++) {
      const size_t m = m0 + wr * 64 + mi * 16 + lg * 4 + r;
      int dst = 0;
      if (EPI == 1) dst = win_to_orig((int)m);
#pragma unroll
      for (int ni = 0; ni < 4; ni++) {
        const int col = colb + ni * 16 + lr;
        gemm_epi<EPI>(acc[mi][ni][r] + bias[col], m, col, N, dst,
                      outb, outf, auxf, auxb);
      }
    }
  }
}

// ---------------- 256x128 BK=32 GEMM, 8 waves (r7-proven template) ---------
// Wave grid 2x4: wave (wr,wc) owns rows wr*128+[0,128), cols wc*32+[0,32).
// For the large-block-count GEMMs (qkv, fc1).
template <int EPI>
__global__ __launch_bounds__(512) void gemm256_kernel(
    const u16* __restrict__ A, const u16* __restrict__ W,
    const float* __restrict__ bias, u16* __restrict__ outb,
    float* __restrict__ outf, const float* __restrict__ auxf,
    const u16* __restrict__ auxb, int K, int N, int NT, int NB) {
  __shared__ __align__(16) short As[16384];   // 2 x (256x32)
  __shared__ __align__(16) short Bs[8192];    // 2 x (128x32)
  const int tid = threadIdx.x, wv = tid >> 6, l = tid & 63;
  const int lr = l & 15, lg = l >> 4;
  int bm, bn;
  {
    const int STS = NT << 3;
    const int body = (NB >> 3) * STS;
    int d = blockIdx.x;
    if (d < body) {
      int st = d / STS, rem = d - st * STS;
      bn = rem >> 3;
      bm = st * 8 + (rem & 7);
    } else {
      int t = d - body;
      int tq = t / NT;
      bm = (NB & ~7) + tq;
      bn = t - tq * NT;
    }
  }
  const size_t m0 = (size_t)bm * 256, n0 = (size_t)bn * 128;
  const int prow = wv * 16 + (l >> 2);
  const int ccl = (((l & 3) ^ ((l >> 3) & 3)) << 3);
  const u16* ga0 = A + (m0 + prow) * K + ccl;
  const u16* ga1 = A + (m0 + 128 + prow) * K + ccl;
  const u16* gb0 = W + (n0 + prow) * K + ccl;
  const int stoff = wv * 512;
  const int wr = wv >> 2, wc = wv & 3;
  const int sw = (lr >> 1) & 3;
  const int aoff = (wr * 128 + lr) * 32 + ((lg ^ sw) << 3);
  const int boff = (wc * 32 + lr) * 32 + ((lg ^ sw) << 3);

#define STAGE(c, koff)                                     \
  do {                                                     \
    GLL16(ga0 + (koff), As + (c) * 8192 + stoff);          \
    GLL16(ga1 + (koff), As + (c) * 8192 + 4096 + stoff);   \
    GLL16(gb0 + (koff), Bs + (c) * 4096 + stoff);          \
  } while (0)
#define FRAG_READS(c)                                                \
  do {                                                               \
    const short* as = As + (c) * 8192;                               \
    const short* bs = Bs + (c) * 4096;                               \
    _Pragma("unroll") for (int mi = 0; mi < 8; mi++)                 \
        af[mi] = *(const s16x8*)&as[aoff + mi * 512];                \
    _Pragma("unroll") for (int ni = 0; ni < 2; ni++)                 \
        bfr[ni] = *(const s16x8*)&bs[boff + ni * 512];               \
  } while (0)
#define MFMA_TILE()                                        \
  do {                                                     \
    __builtin_amdgcn_s_setprio(1);                         \
    _Pragma("unroll") for (int mi = 0; mi < 8; mi++)       \
        _Pragma("unroll") for (int ni = 0; ni < 2; ni++)   \
            acc[mi][ni] = mfma16(af[mi], bfr[ni], acc[mi][ni]); \
    __builtin_amdgcn_s_setprio(0);                         \
  } while (0)

  f32x4 acc[8][2] = {};
  s16x8 af[8], bfr[2];
  STAGE(0, 0);
  STAGE(1, 32);                         // 6 loads in flight
  int cur = 0;
  int k0 = 0;
  for (; k0 < K - 32; k0 += 32) {
    asm volatile("s_waitcnt vmcnt(3)" ::: "memory");
    __builtin_amdgcn_sched_barrier(0);
    __builtin_amdgcn_s_barrier();
    FRAG_READS(cur);
    asm volatile("s_waitcnt lgkmcnt(0)" ::: "memory");
    __builtin_amdgcn_sched_barrier(0);
    __builtin_amdgcn_s_barrier();
    if (k0 + 64 < K) STAGE(cur, k0 + 64);
    MFMA_TILE();
    cur ^= 1;
  }
  asm volatile("s_waitcnt vmcnt(0)" ::: "memory");
  __builtin_amdgcn_sched_barrier(0);
  __builtin_amdgcn_s_barrier();
  FRAG_READS(cur);
  asm volatile("s_waitcnt lgkmcnt(0)" ::: "memory");
  __builtin_amdgcn_sched_barrier(0);
  MFMA_TILE();
#undef STAGE
#undef FRAG_READS
#undef MFMA_TILE

  const int colb = (int)n0 + wc * 32;
#pragma unroll
  for (int mi = 0; mi < 8; mi++) {
#pragma unroll
    for (int r = 0; r < 4; r++) {
      const size_t m = m0 + wr * 128 + mi * 16 + lg * 4 + r;
      int dst = 0;
      if (EPI == 1) dst = win_to_orig((int)m);
#pragma unroll
      for (int ni = 0; ni < 2; ni++) {
        const int col = colb + ni * 16 + lr;
        gemm_epi<EPI>(acc[mi][ni][r] + bias[col], m, col, N, dst,
                      outb, outf, auxf, auxb);
      }
    }
  }
}

// ---------------- windowed attention: 1 wave per (window, head) ------------
__global__ __launch_bounds__(256) void attn_kernel(
    const u16* __restrict__ qkv, const u16* __restrict__ tbl,
    u16* __restrict__ out) {
  __shared__ __align__(16) short Pl[4][16 * 76];
  const int tid = threadIdx.x, wv = tid >> 6, l = tid & 63;
  const int lr = l & 15, lg = l >> 4;

  const int task = blockIdx.x * 4 + wv;          // < 12288 exactly
  const int win = task / 12, h = task - win * 12;
  const int wi = win & 63;
  const short* base = (const short*)qkv + (size_t)win * 49 * 1152 + h * 32;
  const u16* tb = tbl + (size_t)(wi * 12 + h) * 4096 + lr * 4;

  s16x8 qf[4], kf[4];
  const s16x8 zz = {0, 0, 0, 0, 0, 0, 0, 0};
#pragma unroll
  for (int mi = 0; mi < 4; mi++) {
    int n = mi * 16 + lr;
    if (n < 49) {
      qf[mi] = *(const s16x8*)(base + (size_t)n * 1152 + lg * 8);
      kf[mi] = *(const s16x8*)(base + (size_t)n * 1152 + 384 + lg * 8);
    } else { qf[mi] = zz; kf[mi] = zz; }
  }
  s16x8 vb[2][2];
#pragma unroll
  for (int kk = 0; kk < 2; kk++)
#pragma unroll
    for (int nd = 0; nd < 2; nd++)
#pragma unroll
      for (int e = 0; e < 8; e++)
        vb[kk][nd][e] = base[(size_t)(kk * 32 + lg * 8 + e) * 1152 + 768 + nd * 16 + lr];
  u16x4 t4[4][4];
#pragma unroll
  for (int r = 0; r < 4; r++)
    t4[0][r] = *(const u16x4*)&tb[(lg * 4 + r) * 64];

  f32x4 acc[4][4] = {};
  __builtin_amdgcn_s_setprio(1);
#pragma unroll
  for (int mi = 0; mi < 4; mi++)
#pragma unroll
    for (int ni = 0; ni < 4; ni++)
      acc[mi][ni] = mfma16(qf[mi], kf[ni], acc[mi][ni]);
  __builtin_amdgcn_s_setprio(0);

  short* pl = Pl[wv];
#pragma unroll
  for (int mi = 0; mi < 4; mi++) {
    if (mi < 3) {
#pragma unroll
      for (int r = 0; r < 4; r++)
        t4[mi + 1][r] = *(const u16x4*)&tb[((mi + 1) * 16 + lg * 4 + r) * 64];
    }
    float rs[4];
#pragma unroll
    for (int r = 0; r < 4; r++) {
      float sv[4];
#pragma unroll
      for (int ni = 0; ni < 4; ni++)
        sv[ni] = acc[mi][ni][r] * ATTN_SCALE + bf2f(t4[mi][r][ni]);
      float mx = fmaxf(fmaxf(sv[0], sv[1]), fmaxf(sv[2], sv[3]));
#pragma unroll
      for (int d = 1; d < 16; d <<= 1) mx = fmaxf(mx, __shfl_xor(mx, d));
      float sm = 0.f;
#pragma unroll
      for (int ni = 0; ni < 4; ni++) { sv[ni] = __expf(sv[ni] - mx); sm += sv[ni]; }
#pragma unroll
      for (int d = 1; d < 16; d <<= 1) sm += __shfl_xor(sm, d);
      rs[r] = 1.f / sm;
#pragma unroll
      for (int ni = 0; ni < 4; ni++)
        pl[(lg * 4 + r) * 76 + ni * 16 + lr] = (short)f2bf(sv[ni]);
    }
    f32x4 o[2] = {{}, {}};
    __builtin_amdgcn_s_setprio(1);
#pragma unroll
    for (int kk = 0; kk < 2; kk++) {
      s16x8 pa = *(const s16x8*)&pl[lr * 76 + kk * 32 + lg * 8];
#pragma unroll
      for (int nd = 0; nd < 2; nd++)
        o[nd] = mfma16(pa, vb[kk][nd], o[nd]);
    }
    __builtin_amdgcn_s_setprio(0);
#pragma unroll
    for (int r = 0; r < 4; r++) {
      const int irow = mi * 16 + lg * 4 + r;
      if (irow < 49) {
#pragma unroll
        for (int nd = 0; nd < 2; nd++)
          out[((size_t)win * 49 + irow) * 384 + h * 32 + nd * 16 + lr] =
              f2bf(o[nd][r] * rs[r]);
      }
    }
  }
}

extern "C" void kernel_launch(void* const* d_in, const int* in_sizes, int n_in,
                              void* d_out, int out_size, void* d_ws, size_t ws_size,
                              hipStream_t stream) {
  (void)in_sizes; (void)n_in; (void)out_size; (void)ws_size;
  const float* x     = (const float*)d_in[0];
  const float* maskp = (const float*)d_in[1];
  const float* n1g   = (const float*)d_in[2];
  const float* n1b   = (const float*)d_in[3];
  const float* qkvw  = (const float*)d_in[4];
  const float* qkvb  = (const float*)d_in[5];
  const float* rpb   = (const float*)d_in[6];
  const float* projw = (const float*)d_in[7];
  const float* projb = (const float*)d_in[8];
  const float* n2g   = (const float*)d_in[9];
  const float* n2b   = (const float*)d_in[10];
  const float* fc1w  = (const float*)d_in[11];
  const float* fc1b  = (const float*)d_in[12];
  const float* fc2w  = (const float*)d_in[13];
  const float* fc2b  = (const float*)d_in[14];
  float* outp = (float*)d_out;

  // workspace layout, lifetime-shared (r10-proven):
  // A [0, 154140672): qkv (115.6 MB) then h2 (exactly 154.14 MB)
  // B [154140672, +38535168): xw -> attn_out -> xln2
  // C [192675840, +38535168): tbl (6.3 MB, dead after attn) -> xres
  // D [231211008, +3538944): bf16 weights
  char* ws = (char*)d_ws;
  u16*  regA  = (u16*)ws;
  u16*  regB  = (u16*)(ws + 154140672ull);
  u16*  tbl   = (u16*)(ws + 192675840ull);
  u16*  xresb = (u16*)(ws + 192675840ull);
  u16*  wq = (u16*)(ws + 231211008ull);
  u16*  wp = wq + 442368;
  u16*  w1 = wp + 147456;
  u16*  w2 = w1 + 589824;

  // 0. prologue: weights fp32 -> bf16 + bias/mask table (single launch)
  prolog_kernel<<<19200, 256, 0, stream>>>(qkvw, projw, fc1w, fc2w, wq, wp, w1,
                                           w2, rpb, maskp, tbl);
  // 1. LN1 + cyclic shift + window partition (fp32 -> bf16, window order)
  ln_kernel<true, false><<<12544, 256, 0, stream>>>(x, n1g, n1b, regB);
  // 2. QKV projection: (50176x384) @ (384x1152), 256-row tiles
  gemm256_kernel<0><<<196 * 9, 512, 0, stream>>>(regB, wq, qkvb, regA, nullptr,
                                                 nullptr, nullptr, 384, 1152, 9, 196);
  // 3. windowed attention (qkv in A, tbl in C, attn_out -> B)
  attn_kernel<<<3072, 256, 0, stream>>>(regA, tbl, regB);
  // 4. output projection + fp32-x shortcut, un-permute -> bf16 residual (C)
  gemm128_kernel<1><<<392 * 3, 256, 0, stream>>>(regB, wp, projb, xresb, nullptr,
                                                 x, nullptr, 384, 384, 3, 392);
  // 5. LN2 (bf16 xres -> bf16 xln2 in B)
  ln_kernel<false, true><<<12544, 256, 0, stream>>>(xresb, n2g, n2b, regB);
  // 6. FC1 + GELU, full M: (50176x384)@(384x1536) -> h2 in A (qkv dead)
  gemm256_kernel<2><<<196 * 12, 512, 0, stream>>>(regB, w1, fc1b, regA, nullptr,
                                                  nullptr, nullptr, 384, 1536, 12, 196);
  // 7. FC2 + residual, full M -> final fp32 output
  gemm128_kernel<3><<<392 * 3, 256, 0, stream>>>(regA, w2, fc2b, nullptr, outp,
                                                 nullptr, xresb, 1536, 384, 3, 392);
}